// Round 11
// baseline (1055.234 us; speedup 1.0000x reference)
//
#include <hip/hip_runtime.h>
#include <hip/hip_bf16.h>
#include <stdint.h>
#include <stddef.h>

typedef unsigned short u16;
typedef __attribute__((ext_vector_type(8))) short short8;
typedef __attribute__((ext_vector_type(4))) float f32x4;
typedef __attribute__((ext_vector_type(16))) float f32x16;

#define NB 4
#define NL 1024
#define ND 768
#define NH 12
#define NDH 64

__device__ __forceinline__ u16 f2bf(float f) {
  __hip_bfloat16 h = __float2bfloat16(f);
  return *reinterpret_cast<u16*>(&h);
}
__device__ __forceinline__ float bf2f(u16 u) {
  __hip_bfloat16 h;
  *reinterpret_cast<u16*>(&h) = u;
  return __bfloat162float(h);
}

// async global->LDS, 16B per lane. LDS dest is wave-uniform base; HW adds lane*16.
__device__ __forceinline__ void load16_to_lds(const u16* g, u16* l) {
  __builtin_amdgcn_global_load_lds(
      (__attribute__((address_space(1))) void*)(uintptr_t)g,
      (__attribute__((address_space(3))) void*)(uint32_t)(uintptr_t)l,
      16, 0, 0);
}

// ---------------- transpose+cast (q,k) AND fp32->bf16 casts (x,v) in ONE dispatch ----------------
__global__ __launch_bounds__(256) void prep_inputs_kernel(
    const float* __restrict__ qI, const float* __restrict__ kI,
    u16* __restrict__ qT, u16* __restrict__ kTp,
    const float* __restrict__ x, u16* __restrict__ xb, int n4A,
    const float* __restrict__ vI, u16* __restrict__ vb, int n4B) {
  __shared__ float tile[32][33];
  int hz = blockIdx.z;
  if (hz == 2 * NH) {
    int i = (blockIdx.x + 24 * blockIdx.y) * 256 + threadIdx.x;
    int stride = 576 * 256;
    int tot = n4A + n4B;
    for (; i < tot; i += stride) {
      const float4* src;
      ushort4* dst;
      int j;
      if (i < n4A) { src = (const float4*)x; dst = (ushort4*)xb; j = i; }
      else         { src = (const float4*)vI; dst = (ushort4*)vb; j = i - n4A; }
      float4 f = src[j];
      ushort4 o;
      o.x = f2bf(f.x); o.y = f2bf(f.y); o.z = f2bf(f.z); o.w = f2bf(f.w);
      dst[j] = o;
    }
    return;
  }
  int h = (hz < NH) ? hz : hz - NH;
  const float* src = ((hz < NH) ? qI : kI) + (size_t)h * ND * ND;
  u16* dst = ((hz < NH) ? qT : kTp) + (size_t)h * ND * ND;
  int c0 = blockIdx.x * 32, r0 = blockIdx.y * 32;
  int tx = threadIdx.x & 31, ty = threadIdx.x >> 5;
#pragma unroll
  for (int i = 0; i < 32; i += 8)
    tile[ty + i][tx] = src[(size_t)(r0 + ty + i) * ND + c0 + tx];
  __syncthreads();
  int p = tx & 15, j = (tx >> 4) * 8 + ty;
#pragma unroll
  for (int i = 0; i < 32; i += 16) {
    ushort2 o;
    o.x = f2bf(tile[2 * p][j + i]);
    o.y = f2bf(tile[2 * p + 1][j + i]);
    *(ushort2*)&dst[(size_t)(c0 + j + i) * ND + r0 + 2 * p] = o;
  }
}

// ---------------- gemm_prep: MT only (768x768 per head, 6x6 tiles x 12 heads) ----------------
__global__ __launch_bounds__(256, 4) void gemm_prep(
    const u16* __restrict__ kT, const u16* __restrict__ qT, u16* __restrict__ MTp) {
  constexpr int BK = 64;
  constexpr int KDIM = ND;
  constexpr int CPR = BK / 8;
  constexpr long DD = (long)ND * ND;
  __shared__ __align__(16) u16 As[128 * BK];
  __shared__ __align__(16) u16 Bs[128 * BK];

  int id = blockIdx.x + gridDim.x * (blockIdx.y + gridDim.y * blockIdx.z);
  int total = gridDim.x * gridDim.y * gridDim.z;  // 432, %8==0
  int per = total >> 3;
  int wk = (id & 7) * per + (id >> 3);
  int xx = wk % gridDim.x;
  int g2 = wk / gridDim.x;
  int yy = g2 % gridDim.y;
  int zz = g2 / gridDim.y;

  const u16* A = kT + (size_t)zz * DD;
  const u16* Bm = qT + (size_t)zz * DD;
  u16* C = MTp + (size_t)zz * DD;

  int m0 = yy * 128, n0 = xx * 128;
  int t = threadIdx.x;
  int lane = t & 63, w = t >> 6;
  int m32 = lane & 31, kg = lane >> 5;
  int wm = w >> 1, wn = w & 1;

  const u16* gAb;
  const u16* gBb;
  {
    int r = t / CPR;
    int cc = (t & (CPR - 1)) ^ (r & 7);
    gAb = A + (size_t)(m0 + r) * KDIM + cc * 8;
    gBb = Bm + (size_t)(n0 + r) * KDIM + cc * 8;
  }

  f32x16 acc[2][2];
#pragma unroll
  for (int i = 0; i < 2; i++)
#pragma unroll
    for (int j = 0; j < 2; j++)
#pragma unroll
      for (int r = 0; r < 16; r++) acc[i][j][r] = 0.f;

#pragma unroll 1
  for (int k0 = 0; k0 < KDIM; k0 += BK) {
    __syncthreads();
#pragma unroll
    for (int u = 0; u < 4; u++)
      load16_to_lds(gAb + (size_t)u * 32 * KDIM, &As[(size_t)(u * 256 + w * 64) * 8]);
    gAb += BK;
#pragma unroll
    for (int u = 0; u < 4; u++)
      load16_to_lds(gBb + (size_t)u * 32 * KDIM, &Bs[(size_t)(u * 256 + w * 64) * 8]);
    gBb += BK;
    __syncthreads();

#pragma unroll
    for (int kc = 0; kc < 2; kc++) {
      short8 af[2][2], bfr[2][2];
#pragma unroll
      for (int i = 0; i < 2; i++) {
        int row = wm * 64 + i * 32 + m32;
#pragma unroll
        for (int h = 0; h < 2; h++) {
          int ck = (kc * 4 + h * 2 + kg) ^ (row & 7);
          af[i][h] = *(const short8*)&As[row * BK + ck * 8];
        }
      }
#pragma unroll
      for (int j = 0; j < 2; j++) {
        int row = wn * 64 + j * 32 + m32;
#pragma unroll
        for (int h = 0; h < 2; h++) {
          int ck = (kc * 4 + h * 2 + kg) ^ (row & 7);
          bfr[j][h] = *(const short8*)&Bs[row * BK + ck * 8];
        }
      }
#pragma unroll
      for (int i = 0; i < 2; i++)
#pragma unroll
        for (int j = 0; j < 2; j++) {
          acc[i][j] = __builtin_amdgcn_mfma_f32_32x32x16_bf16(af[i][0], bfr[j][0], acc[i][j], 0, 0, 0);
          acc[i][j] = __builtin_amdgcn_mfma_f32_32x32x16_bf16(af[i][1], bfr[j][1], acc[i][j], 0, 0, 0);
        }
    }
  }

#pragma unroll
  for (int i = 0; i < 2; i++) {
#pragma unroll
    for (int j = 0; j < 2; j++) {
      int colg = n0 + wn * 64 + j * 32 + m32;
#pragma unroll
      for (int r = 0; r < 16; r++) {
        int rowg = m0 + wm * 64 + i * 32 + (r & 3) + 8 * (r >> 2) + 4 * kg;
        C[(size_t)rowg * ND + colg] = f2bf(acc[i][j][r]);
      }
    }
  }
}

// ---------------- gemm_TV2: T slices (zz<cT) + batched V2 (zz>=cT) in ONE dispatch ----------------
__global__ __launch_bounds__(256, 4) void gemm_TV2(
    const u16* __restrict__ xb, const u16* __restrict__ MTp, u16* __restrict__ Tout,
    const u16* __restrict__ vb, u16* __restrict__ V2p, int p0, int cT) {
  constexpr int BK = 64;
  constexpr int KDIM = ND;
  constexpr int CPR = BK / 8;
  constexpr long DD = (long)ND * ND;
  constexpr long LD = (long)NL * ND;
  __shared__ __align__(16) u16 As[128 * BK];
  __shared__ __align__(16) u16 Bs[128 * BK];

  int id = blockIdx.x + gridDim.x * (blockIdx.y + gridDim.y * blockIdx.z);
  int total = gridDim.x * gridDim.y * gridDim.z;
  int per = total >> 3;
  int wk = (id & 7) * per + (id >> 3);
  int xx = wk % gridDim.x;   // 8 range
  int g2 = wk / gridDim.x;
  int yy = g2 % gridDim.y;   // 6 range
  int zz = g2 / gridDim.y;

  const u16* A;
  const u16* Bm;
  u16* C;
  int ldc, m0, n0;
  if (zz < cT) {
    int g = p0 + zz;
    int b = g / NH, n = g % NH;
    A = xb + (size_t)b * LD;
    Bm = MTp + (size_t)n * DD;
    C = Tout + (size_t)zz * LD;
    ldc = ND;
    m0 = xx * 128;
    n0 = yy * 128;
  } else {
    int b = zz - cT;
    A = vb;
    Bm = xb + (size_t)b * LD;
    C = V2p + (size_t)b * NH * NDH * NL;
    ldc = NL;
    m0 = yy * 128;
    n0 = xx * 128;
  }

  int t = threadIdx.x;
  int lane = t & 63, w = t >> 6;
  int m32 = lane & 31, kg = lane >> 5;
  int wm = w >> 1, wn = w & 1;

  const u16* gAb;
  const u16* gBb;
  {
    int r = t / CPR;
    int cc = (t & (CPR - 1)) ^ (r & 7);
    gAb = A + (size_t)(m0 + r) * KDIM + cc * 8;
    gBb = Bm + (size_t)(n0 + r) * KDIM + cc * 8;
  }

  f32x16 acc[2][2];
#pragma unroll
  for (int i = 0; i < 2; i++)
#pragma unroll
    for (int j = 0; j < 2; j++)
#pragma unroll
      for (int r = 0; r < 16; r++) acc[i][j][r] = 0.f;

#pragma unroll 1
  for (int k0 = 0; k0 < KDIM; k0 += BK) {
    __syncthreads();
#pragma unroll
    for (int u = 0; u < 4; u++)
      load16_to_lds(gAb + (size_t)u * 32 * KDIM, &As[(size_t)(u * 256 + w * 64) * 8]);
    gAb += BK;
#pragma unroll
    for (int u = 0; u < 4; u++)
      load16_to_lds(gBb + (size_t)u * 32 * KDIM, &Bs[(size_t)(u * 256 + w * 64) * 8]);
    gBb += BK;
    __syncthreads();

#pragma unroll
    for (int kc = 0; kc < 2; kc++) {
      short8 af[2][2], bfr[2][2];
#pragma unroll
      for (int i = 0; i < 2; i++) {
        int row = wm * 64 + i * 32 + m32;
#pragma unroll
        for (int h = 0; h < 2; h++) {
          int ck = (kc * 4 + h * 2 + kg) ^ (row & 7);
          af[i][h] = *(const short8*)&As[row * BK + ck * 8];
        }
      }
#pragma unroll
      for (int j = 0; j < 2; j++) {
        int row = wn * 64 + j * 32 + m32;
#pragma unroll
        for (int h = 0; h < 2; h++) {
          int ck = (kc * 4 + h * 2 + kg) ^ (row & 7);
          bfr[j][h] = *(const short8*)&Bs[row * BK + ck * 8];
        }
      }
#pragma unroll
      for (int i = 0; i < 2; i++)
#pragma unroll
        for (int j = 0; j < 2; j++) {
          acc[i][j] = __builtin_amdgcn_mfma_f32_32x32x16_bf16(af[i][0], bfr[j][0], acc[i][j], 0, 0, 0);
          acc[i][j] = __builtin_amdgcn_mfma_f32_32x32x16_bf16(af[i][1], bfr[j][1], acc[i][j], 0, 0, 0);
        }
    }
  }

#pragma unroll
  for (int i = 0; i < 2; i++) {
#pragma unroll
    for (int j = 0; j < 2; j++) {
      int colg = n0 + wn * 64 + j * 32 + m32;
#pragma unroll
      for (int r = 0; r < 16; r++) {
        int rowg = m0 + wm * 64 + i * 32 + (r & 3) + 8 * (r >> 2) + 4 * kg;
        C[(size_t)rowg * ldc + colg] = f2bf(acc[i][j][r]);
      }
    }
  }
}

// ---------------- gemm256_bk32: 256x256 tile, BK=32, 8-phase, 2 BLOCKS/CU ----------------
// Halved-BK variant of the verified 8-phase kernel: LDS 64 KB -> 2 blocks/CU (16 waves/CU
// at 128 VGPR) so cross-block TLP fills the barrier-skew gaps (m114 mechanism; same lever
// that gives the 128^2/4-blk kernel its throughput without scheduling tricks).
// Per tile: 4 staging calls (128 rows x 64B each); ledger: ph2:{A-c0,B-c0(t+2)},
// ph3:B-c1, ph4:A-c1 + vmcnt(4); ph6-8 mirror into buf1 for t+3. Each slot staged
// one phase after its last ds_read (A rows0-127 read ph1; B rows0-127 ph1; B rows
// 128-255 ph2; A rows128-255 ph3). vmcnt(4) leaves exactly the next tile's 4 calls
// in flight. Swizzle: store chunk (t&3)^(row&3), read ck=q4^(row&3) — bijective,
// wave covers a contiguous 1KB block.
// OUTMODE: 1 = bf16, 2 = bf16(exp(v)).
template <int OUTMODE, int KDIM, int LDC>
__global__ __launch_bounds__(512, 4) void gemm256_bk32(
    const u16* __restrict__ A, const u16* __restrict__ Bm, void* __restrict__ Cv,
    long sAb, long sAn, long sAz,
    long sBb, long sBn, long sBz,
    long sCb, long sCn, long sCz,
    int p0) {
  constexpr int BK = 32;
  constexpr int NT = KDIM / BK;   // 24
  constexpr int NC = NT / 2;      // 12
  static_assert(KDIM % 64 == 0 && NC >= 2, "need even #K-tiles and >=2 cycles");
  __shared__ __align__(16) u16 As[2][256 * BK];  // 32 KB
  __shared__ __align__(16) u16 Bs[2][256 * BK];  // 32 KB

  int id = blockIdx.x + gridDim.x * (blockIdx.y + gridDim.y * blockIdx.z);
  int total = gridDim.x * gridDim.y * gridDim.z;
  int xx, yy, zz;
  if ((total & 7) == 0) {
    int per = total >> 3;
    int wk = (id & 7) * per + (id >> 3);
    xx = wk % gridDim.x;
    int g2 = wk / gridDim.x;
    yy = g2 % gridDim.y;
    zz = g2 / gridDim.y;
  } else {
    xx = blockIdx.x; yy = blockIdx.y; zz = blockIdx.z;
  }

  int g = p0 + zz;
  int b = g / NH, n = g % NH;
  A  += (size_t)b * sAb + (size_t)n * sAn + (size_t)zz * sAz;
  Bm += (size_t)b * sBb + (size_t)n * sBn + (size_t)zz * sBz;
  size_t cOff = (size_t)b * sCb + (size_t)n * sCn + (size_t)zz * sCz;

  int m0 = yy * 256, n0 = xx * 256;
  int t = threadIdx.x;
  int lane = t & 63, w = t >> 6;
  int wm = w >> 2, wn = w & 3;
  int l15 = lane & 15, q4 = lane >> 4;

  // staging: call covers 128 rows x 32 cols; thread t -> row t>>2, chunk t&3 (16B units);
  // source pre-swizzled by ^(row&3) so linear LDS dest + XOR'd read are consistent.
  int r0c = t >> 2;
  int cc0 = (t & 3) ^ (r0c & 3);
  const u16* gA = A + (size_t)(m0 + r0c) * KDIM + cc0 * 8;
  const u16* gB = Bm + (size_t)(n0 + r0c) * KDIM + cc0 * 8;
  int wslab = w * 512;  // per-wave u16 offset within a call slab (64 thr x 8 u16)

#define STG_A1(d, u, kt) load16_to_lds( \
    gA + (size_t)(u) * 128 * KDIM + (size_t)(kt) * BK, \
    &As[d][(u) * 4096 + wslab])
#define STG_B1(d, u, kt) load16_to_lds( \
    gB + (size_t)(u) * 128 * KDIM + (size_t)(kt) * BK, \
    &Bs[d][(u) * 4096 + wslab])

#define READ_A(d, qm, dst) do { \
  _Pragma("unroll") for (int fm = 0; fm < 4; fm++) { \
    int row = (qm) * 128 + wm * 64 + fm * 16 + l15; \
    int ck = q4 ^ (row & 3); \
    dst[fm] = *(const short8*)&As[d][row * BK + ck * 8]; \
  } \
} while (0)

#define READ_B(d, qn, dst) do { \
  _Pragma("unroll") for (int fn = 0; fn < 2; fn++) { \
    int row = (qn) * 128 + wn * 32 + fn * 16 + l15; \
    int ck = q4 ^ (row & 3); \
    dst[fn] = *(const short8*)&Bs[d][row * BK + ck * 8]; \
  } \
} while (0)

#define MF_Q(qm, qn, AR, BR) do { \
  __builtin_amdgcn_s_setprio(1); \
  _Pragma("unroll") for (int fm = 0; fm < 4; fm++) \
    _Pragma("unroll") for (int fn = 0; fn < 2; fn++) \
      acc[qm][qn][fm][fn] = __builtin_amdgcn_mfma_f32_16x16x32_bf16( \
          AR[fm], BR[fn], acc[qm][qn][fm][fn], 0, 0, 0); \
  __builtin_amdgcn_s_setprio(0); \
} while (0)

#define PH_SYNC() do { \
  __builtin_amdgcn_s_barrier(); \
  asm volatile("s_waitcnt lgkmcnt(0)" ::: "memory"); \
  __builtin_amdgcn_sched_barrier(0); \
} while (0)
#define PH_END() do { \
  __builtin_amdgcn_s_barrier(); \
  __builtin_amdgcn_sched_barrier(0); \
} while (0)

  f32x4 acc[2][2][4][2];
#pragma unroll
  for (int qm = 0; qm < 2; qm++)
#pragma unroll
    for (int qn = 0; qn < 2; qn++)
#pragma unroll
      for (int fm = 0; fm < 4; fm++)
#pragma unroll
        for (int fn = 0; fn < 2; fn++)
          acc[qm][qn][fm][fn] = (f32x4){0.f, 0.f, 0.f, 0.f};

  // prologue: tile0 -> buf0 (4 calls), tile1 -> buf1 (4 calls); vmcnt(4): tile0 landed
  STG_A1(0, 0, 0); STG_A1(0, 1, 0);
  STG_B1(0, 0, 0); STG_B1(0, 1, 0);
  STG_A1(1, 0, 1); STG_A1(1, 1, 1);
  STG_B1(1, 0, 1); STG_B1(1, 1, 1);
  asm volatile("s_waitcnt vmcnt(4)" ::: "memory");
  __builtin_amdgcn_s_barrier();
  __builtin_amdgcn_sched_barrier(0);

#pragma unroll 1
  for (int cyc = 0; cyc < NC; ++cyc) {
    int t0 = cyc * 2;
    bool full = (cyc + 1 < NC);
    short8 af0[4], af1[4], bq0[2], bq1[2];

    // ---- K-tile t0 from buf0 ----
    // ph1: Q(0,0); no stage
    READ_A(0, 0, af0); READ_B(0, 0, bq0);
    PH_SYNC(); MF_Q(0, 0, af0, bq0); PH_END();
    // ph2: Q(0,1); stage A-c0 + B-c0 (t+2 -> buf0; rows 0-127, last read ph1)
    READ_B(0, 1, bq1);
    if (full) { STG_A1(0, 0, t0 + 2); STG_B1(0, 0, t0 + 2); }
    PH_SYNC(); MF_Q(0, 1, af0, bq1); PH_END();
    // ph3: Q(1,0); stage B-c1 (t+2; B rows 128-255 last read ph2)
    READ_A(0, 1, af1);
    if (full) STG_B1(0, 1, t0 + 2);
    PH_SYNC(); MF_Q(1, 0, af1, bq0); PH_END();
    // ph4: Q(1,1); stage A-c1 (t+2; A rows 128-255 last read ph3); vmcnt for tile t0+1
    if (full) STG_A1(0, 1, t0 + 2);
    __builtin_amdgcn_s_barrier();
    MF_Q(1, 1, af1, bq1);
    __builtin_amdgcn_sched_barrier(0);
    if (full) asm volatile("s_waitcnt vmcnt(4)" ::: "memory");
    else      asm volatile("s_waitcnt vmcnt(0)" ::: "memory");
    PH_END();

    // ---- K-tile t0+1 from buf1 ----
    // ph5: Q(0,0); no stage
    READ_A(1, 0, af0); READ_B(1, 0, bq0);
    PH_SYNC(); MF_Q(0, 0, af0, bq0); PH_END();
    // ph6: Q(0,1); stage A-c0 + B-c0 (t+3 -> buf1)
    READ_B(1, 1, bq1);
    if (full) { STG_A1(1, 0, t0 + 3); STG_B1(1, 0, t0 + 3); }
    PH_SYNC(); MF_Q(0, 1, af0, bq1); PH_END();
    // ph7: Q(1,0); stage B-c1 (t+3)
    READ_A(1, 1, af1);
    if (full) STG_B1(1, 1, t0 + 3);
    PH_SYNC(); MF_Q(1, 0, af1, bq0); PH_END();
    // ph8: Q(1,1); stage A-c1 (t+3); vmcnt for tile t0+2
    if (full) {
      STG_A1(1, 1, t0 + 3);
      __builtin_amdgcn_s_barrier();
      MF_Q(1, 1, af1, bq1);
      __builtin_amdgcn_sched_barrier(0);
      asm volatile("s_waitcnt vmcnt(4)" ::: "memory");
      PH_END();
    } else {
      __builtin_amdgcn_s_barrier();
      MF_Q(1, 1, af1, bq1);
    }
  }

  // epilogue: 16x16 frag C/D map: row = q4*4 + r, col = l15
#pragma unroll
  for (int qm = 0; qm < 2; qm++)
#pragma unroll
    for (int qn = 0; qn < 2; qn++)
#pragma unroll
      for (int fm = 0; fm < 4; fm++)
#pragma unroll
        for (int fn = 0; fn < 2; fn++) {
          int colg = n0 + qn * 128 + wn * 32 + fn * 16 + l15;
#pragma unroll
          for (int r = 0; r < 4; r++) {
            int rowg = m0 + qm * 128 + wm * 64 + fm * 16 + q4 * 4 + r;
            float vv = acc[qm][qn][fm][fn][r];
            if (OUTMODE == 2) vv = __expf(vv);
            ((u16*)Cv)[cOff + (size_t)rowg * LDC + colg] = f2bf(vv);
          }
        }
#undef STG_A1
#undef STG_B1
#undef READ_A
#undef READ_B
#undef MF_Q
#undef PH_SYNC
#undef PH_END
}

// ---------------- fused PV (+ divide) over precomputed P = exp(S) ----------------
__global__ __launch_bounds__(256) void softmax_pv_kernel(
    const u16* __restrict__ Pb, const u16* __restrict__ V2, float* __restrict__ out,
    int p0) {
  __shared__ __align__(16) u16 Ps[64 * 128];  // 16 KB
  __shared__ __align__(16) u16 Vs[64 * 128];  // 16 KB

  int id = blockIdx.x + gridDim.x * blockIdx.y;
  int total = gridDim.x * gridDim.y;
  int xx, zz;
  if ((total & 7) == 0) {
    int per = total >> 3;
    int wk = (id & 7) * per + (id >> 3);
    xx = wk & 15; zz = wk >> 4;
  } else {
    xx = blockIdx.x; zz = blockIdx.y;
  }

  int g = p0 + zz;
  int b = g / NH, n = g % NH;
  const u16* S = Pb + (size_t)zz * NL * NL;
  const u16* V = V2 + (size_t)g * NDH * NL;

  int l0 = xx * 64;
  int t = threadIdx.x;
  int lane = t & 63, w = t >> 6;
  int row16 = lane & 15, q = lane >> 4;
  int rs = row16 & 7;

  f32x4 acc[5];
#pragma unroll
  for (int j = 0; j < 5; j++) acc[j] = (f32x4){0.f, 0.f, 0.f, 0.f};

  short8 onesf;
  {
    short val = (row16 == 0) ? (short)0x3F80 : (short)0;
#pragma unroll
    for (int e = 0; e < 8; e++) onesf[e] = val;
  }

  const u16* ssrc[4];
  const u16* vsrc[4];
#pragma unroll
  for (int u = 0; u < 4; u++) {
    int c = u * 256 + t;
    int r = c >> 4, cc = (c & 15) ^ (r & 7);
    ssrc[u] = S + (size_t)(l0 + r) * NL + cc * 8;
    vsrc[u] = V + (size_t)r * NL + cc * 8;
  }

#pragma unroll 1
  for (int mt = 0; mt < 8; mt++) {
    int mo = mt * 128;
    __syncthreads();
#pragma unroll
    for (int u = 0; u < 4; u++)
      load16_to_lds(ssrc[u] + mo, &Ps[(size_t)(u * 256 + w * 64) * 8]);
#pragma unroll
    for (int u = 0; u < 4; u++)
      load16_to_lds(vsrc[u] + mo, &Vs[(size_t)(u * 256 + w * 64) * 8]);
    __syncthreads();

#pragma unroll
    for (int kk = 0; kk < 4; kk++) {
      int ch = ((kk * 4 + q) ^ rs) * 16;
      int lrow = w * 16 + row16;
      // P already exp'd (fused into the Sb GEMM epilogue) — feed raw.
      short8 paf = *(const short8*)((const char*)Ps + lrow * 256 + ch);
      short8 bfr[4];
#pragma unroll
      for (int j = 0; j < 4; j++) {
        int dh = j * 16 + row16;
        bfr[j] = *(const short8*)((const char*)Vs + dh * 256 + ch);
      }
#pragma unroll
      for (int j = 0; j < 4; j++)
        acc[j] = __builtin_amdgcn_mfma_f32_16x16x32_bf16(paf, bfr[j], acc[j], 0, 0, 0);
      acc[4] = __builtin_amdgcn_mfma_f32_16x16x32_bf16(paf, onesf, acc[4], 0, 0, 0);
    }
  }

#pragma unroll
  for (int r = 0; r < 4; r++) {
    float sum = __shfl(acc[4][r], lane & 48, 64);
    float inv = 1.0f / sum;
    int row = l0 + w * 16 + q * 4 + r;
    float* op = out + ((size_t)b * NL + row) * ND + n * NDH;
#pragma unroll
    for (int j = 0; j < 4; j++)
      op[j * 16 + row16] = acc[j][r] * inv;
  }
}

extern "C" void kernel_launch(void* const* d_in, const int* in_sizes, int n_in,
                              void* d_out, int out_size, void* d_ws, size_t ws_size,
                              hipStream_t stream) {
  (void)in_sizes; (void)n_in; (void)out_size;
  const float* x  = (const float*)d_in[0];
  const float* kI = (const float*)d_in[1];
  const float* qI = (const float*)d_in[2];
  const float* vI = (const float*)d_in[3];
  float* out = (float*)d_out;

  size_t off = 0;
  char* wsb = (char*)d_ws;
  auto alloc = [&](size_t bytes) -> char* {
    char* p = wsb + off;
    off += (bytes + 255) & ~(size_t)255;
    return p;
  };
  // ---- fixed (live across whole launch) ----
  u16* xb = (u16*)alloc((size_t)NB * NL * ND * 2);        // 12.6 MB
  u16* vb = (u16*)alloc((size_t)NH * NDH * ND * 2);       //  2.4 MB
  u16* MT = (u16*)alloc((size_t)NH * ND * ND * 2);        // 28.3 MB
  u16* V2 = (u16*)alloc((size_t)NB * NH * NDH * NL * 2);  //  6.3 MB
  size_t fixedSz = off;

  // ---- scratch: qT/kT live only until gemm_prep; T/Sb overlay the same region.
  u16* qT = (u16*)alloc((size_t)NH * ND * ND * 2);        // 28.3 MB
  u16* kT = (u16*)alloc((size_t)NH * ND * ND * 2);        // 28.3 MB
  size_t scratchEndQK = off;

  const size_t Tsz  = (size_t)NL * ND * 2;
  const size_t Ssz  = (size_t)NL * NL * 2;
  const size_t perPair = Tsz + Ssz;

  int chunk = NB * NH;  // 48
  {
    size_t avail = ws_size > fixedSz ? ws_size - fixedSz : 0;
    size_t maxChunk = avail / perPair;
    if (maxChunk < 1) maxChunk = 1;
    if (maxChunk < (size_t)chunk) {
      int passes = (int)(((size_t)NB * NH + maxChunk - 1) / maxChunk);
      chunk = (NB * NH + passes - 1) / passes;
    }
  }
  off = fixedSz;
  u16* T  = (u16*)alloc((size_t)chunk * Tsz);
  u16* Sb = (u16*)alloc((size_t)chunk * Ssz);
  if (off < scratchEndQK) off = scratchEndQK;

  const long LD  = (long)NL * ND;
  const long LL  = (long)NL * NL;

  {
    int n4A = NB * NL * ND / 4;
    int n4B = NH * NDH * ND / 4;
    prep_inputs_kernel<<<dim3(24, 24, 2 * NH + 1), dim3(256), 0, stream>>>(
        qI, kI, qT, kT, x, xb, n4A, vI, vb, n4B);
  }

  // MT only: grid 6x6x12 = 432 blocks
  gemm_prep<<<dim3(6, 6, 12), dim3(256), 0, stream>>>(kT, qT, MT);

  for (int p0 = 0; p0 < NB * NH; p0 += chunk) {
    int c = NB * NH - p0;
    if (c > chunk) c = chunk;
    // T slices (+ batched V2 on first pass, filling T's ragged tail): 128^2, 4 blk/CU
    int zT = c + ((p0 == 0) ? NB : 0);
    gemm_TV2<<<dim3(8, 6, zT), dim3(256), 0, stream>>>(xb, MT, T, vb, V2, p0, c);
    // P[z][l][m] = exp(sum_e T[z][l][e]*xb[b][m][e])  (1024x1024, K=768)
    // BK=32 / 64KB-LDS / 2 blocks-per-CU 8-phase
    gemm256_bk32<2, 768, NL><<<dim3(4, 4, c), dim3(512), 0, stream>>>(
        T, xb, Sb,
        0, 0, LD,  LD, 0, 0,  0, 0, LL, p0);
    // PV + divide -> writes out directly
    softmax_pv_kernel<<<dim3(16, c), dim3(256), 0, stream>>>(Sb, V2, out, p0);
  }
}

// Round 12
// 290.087 us; speedup vs baseline: 3.6376x; 3.6376x over previous
//
#include <hip/hip_runtime.h>
#include <hip/hip_bf16.h>
#include <stdint.h>
#include <stddef.h>

typedef unsigned short u16;
typedef __attribute__((ext_vector_type(8))) short short8;
typedef __attribute__((ext_vector_type(4))) float f32x4;
typedef __attribute__((ext_vector_type(16))) float f32x16;

#define NB 4
#define NL 1024
#define ND 768
#define NH 12
#define NDH 64

__device__ __forceinline__ u16 f2bf(float f) {
  __hip_bfloat16 h = __float2bfloat16(f);
  return *reinterpret_cast<u16*>(&h);
}
__device__ __forceinline__ float bf2f(u16 u) {
  __hip_bfloat16 h;
  *reinterpret_cast<u16*>(&h) = u;
  return __bfloat162float(h);
}

// async global->LDS, 16B per lane. LDS dest is wave-uniform base; HW adds lane*16.
__device__ __forceinline__ void load16_to_lds(const u16* g, u16* l) {
  __builtin_amdgcn_global_load_lds(
      (__attribute__((address_space(1))) void*)(uintptr_t)g,
      (__attribute__((address_space(3))) void*)(uint32_t)(uintptr_t)l,
      16, 0, 0);
}

// ---------------- transpose+cast (q,k) AND fp32->bf16 casts (x,v) in ONE dispatch ----------------
__global__ __launch_bounds__(256) void prep_inputs_kernel(
    const float* __restrict__ qI, const float* __restrict__ kI,
    u16* __restrict__ qT, u16* __restrict__ kTp,
    const float* __restrict__ x, u16* __restrict__ xb, int n4A,
    const float* __restrict__ vI, u16* __restrict__ vb, int n4B) {
  __shared__ float tile[32][33];
  int hz = blockIdx.z;
  if (hz == 2 * NH) {
    int i = (blockIdx.x + 24 * blockIdx.y) * 256 + threadIdx.x;
    int stride = 576 * 256;
    int tot = n4A + n4B;
    for (; i < tot; i += stride) {
      const float4* src;
      ushort4* dst;
      int j;
      if (i < n4A) { src = (const float4*)x; dst = (ushort4*)xb; j = i; }
      else         { src = (const float4*)vI; dst = (ushort4*)vb; j = i - n4A; }
      float4 f = src[j];
      ushort4 o;
      o.x = f2bf(f.x); o.y = f2bf(f.y); o.z = f2bf(f.z); o.w = f2bf(f.w);
      dst[j] = o;
    }
    return;
  }
  int h = (hz < NH) ? hz : hz - NH;
  const float* src = ((hz < NH) ? qI : kI) + (size_t)h * ND * ND;
  u16* dst = ((hz < NH) ? qT : kTp) + (size_t)h * ND * ND;
  int c0 = blockIdx.x * 32, r0 = blockIdx.y * 32;
  int tx = threadIdx.x & 31, ty = threadIdx.x >> 5;
#pragma unroll
  for (int i = 0; i < 32; i += 8)
    tile[ty + i][tx] = src[(size_t)(r0 + ty + i) * ND + c0 + tx];
  __syncthreads();
  int p = tx & 15, j = (tx >> 4) * 8 + ty;
#pragma unroll
  for (int i = 0; i < 32; i += 16) {
    ushort2 o;
    o.x = f2bf(tile[2 * p][j + i]);
    o.y = f2bf(tile[2 * p + 1][j + i]);
    *(ushort2*)&dst[(size_t)(c0 + j + i) * ND + r0 + 2 * p] = o;
  }
}

// ---------------- gemm_bt: 128^2 structure (4 blocks/CU) ----------------
template <bool BF16_OUT, int IM, int IN, int KDIM, int LDC>
__global__ __launch_bounds__(256, 4) void gemm_bt(
    const u16* __restrict__ A, const u16* __restrict__ Bm, void* __restrict__ Cv,
    long sAb, long sAn, long sAz,
    long sBb, long sBn, long sBz,
    long sCb, long sCn, long sCz,
    int p0) {
  constexpr int BK = 64;
  constexpr int MTILE = IM * 64;
  constexpr int NTILE = IN * 64;
  constexpr int CPR = BK / 8;
  constexpr int ACH = MTILE * CPR / 256;
  constexpr int BCH = NTILE * CPR / 256;
  __shared__ __align__(16) u16 As[MTILE * BK];
  __shared__ __align__(16) u16 Bs[NTILE * BK];

  int id = blockIdx.x + gridDim.x * (blockIdx.y + gridDim.y * blockIdx.z);
  int total = gridDim.x * gridDim.y * gridDim.z;
  int xx, yy, zz;
  if ((total & 7) == 0) {
    int per = total >> 3;
    int wk = (id & 7) * per + (id >> 3);
    xx = wk % gridDim.x;
    int g2 = wk / gridDim.x;
    yy = g2 % gridDim.y;
    zz = g2 / gridDim.y;
  } else {
    xx = blockIdx.x; yy = blockIdx.y; zz = blockIdx.z;
  }

  int g = p0 + zz;
  int b = g / NH, n = g % NH;
  A  += (size_t)b * sAb + (size_t)n * sAn + (size_t)zz * sAz;
  Bm += (size_t)b * sBb + (size_t)n * sBn + (size_t)zz * sBz;
  size_t cOff = (size_t)b * sCb + (size_t)n * sCn + (size_t)zz * sCz;

  int m0 = yy * MTILE, n0 = xx * NTILE;
  int t = threadIdx.x;
  int lane = t & 63, w = t >> 6;
  int m32 = lane & 31, kg = lane >> 5;
  int wm = w >> 1, wn = w & 1;

  const u16* gAb;
  const u16* gBb;
  {
    int r = t / CPR;
    int cc = (t & (CPR - 1)) ^ (r & 7);
    gAb = A + (size_t)(m0 + r) * KDIM + cc * 8;
    gBb = Bm + (size_t)(n0 + r) * KDIM + cc * 8;
  }

  f32x16 acc[IM][IN];
#pragma unroll
  for (int i = 0; i < IM; i++)
#pragma unroll
    for (int j = 0; j < IN; j++)
#pragma unroll
      for (int r = 0; r < 16; r++) acc[i][j][r] = 0.f;

#pragma unroll 1
  for (int k0 = 0; k0 < KDIM; k0 += BK) {
    __syncthreads();
#pragma unroll
    for (int u = 0; u < ACH; u++)
      load16_to_lds(gAb + (size_t)u * 32 * KDIM, &As[(size_t)(u * 256 + w * 64) * 8]);
    gAb += BK;
#pragma unroll
    for (int u = 0; u < BCH; u++)
      load16_to_lds(gBb + (size_t)u * 32 * KDIM, &Bs[(size_t)(u * 256 + w * 64) * 8]);
    gBb += BK;
    __syncthreads();

#pragma unroll
    for (int kc = 0; kc < 2; kc++) {
      short8 af[IM][2], bfr[IN][2];
#pragma unroll
      for (int i = 0; i < IM; i++) {
        int row = wm * (IM * 32) + i * 32 + m32;
#pragma unroll
        for (int h = 0; h < 2; h++) {
          int ck = (kc * 4 + h * 2 + kg) ^ (row & 7);
          af[i][h] = *(const short8*)&As[row * BK + ck * 8];
        }
      }
#pragma unroll
      for (int j = 0; j < IN; j++) {
        int row = wn * (IN * 32) + j * 32 + m32;
#pragma unroll
        for (int h = 0; h < 2; h++) {
          int ck = (kc * 4 + h * 2 + kg) ^ (row & 7);
          bfr[j][h] = *(const short8*)&Bs[row * BK + ck * 8];
        }
      }
#pragma unroll
      for (int i = 0; i < IM; i++)
#pragma unroll
        for (int j = 0; j < IN; j++) {
          acc[i][j] = __builtin_amdgcn_mfma_f32_32x32x16_bf16(af[i][0], bfr[j][0], acc[i][j], 0, 0, 0);
          acc[i][j] = __builtin_amdgcn_mfma_f32_32x32x16_bf16(af[i][1], bfr[j][1], acc[i][j], 0, 0, 0);
        }
    }
  }

#pragma unroll
  for (int i = 0; i < IM; i++) {
#pragma unroll
    for (int j = 0; j < IN; j++) {
      int colg = n0 + wn * (IN * 32) + j * 32 + m32;
#pragma unroll
      for (int r = 0; r < 16; r++) {
        int rowg = m0 + wm * (IM * 32) + i * 32 + (r & 3) + 8 * (r >> 2) + 4 * kg;
        float vv = acc[i][j][r];
        if (BF16_OUT) {
          ((u16*)Cv)[cOff + (size_t)rowg * LDC + colg] = f2bf(vv);
        } else {
          ((float*)Cv)[cOff + (size_t)rowg * LDC + colg] = vv;
        }
      }
    }
  }
}

// ---------------- gemm_prep: MT (zz<12) and batched V2 (zz>=12) in ONE dispatch ----------------
__global__ __launch_bounds__(256, 4) void gemm_prep(
    const u16* __restrict__ kT, const u16* __restrict__ qT, u16* __restrict__ MTp,
    const u16* __restrict__ vb, const u16* __restrict__ xb, u16* __restrict__ V2p) {
  constexpr int BK = 64;
  constexpr int KDIM = ND;
  constexpr int CPR = BK / 8;
  constexpr long DD = (long)ND * ND;
  constexpr long LD = (long)NL * ND;
  __shared__ __align__(16) u16 As[128 * BK];
  __shared__ __align__(16) u16 Bs[128 * BK];

  int id = blockIdx.x + gridDim.x * (blockIdx.y + gridDim.y * blockIdx.z);
  int total = gridDim.x * gridDim.y * gridDim.z;  // 768
  int per = total >> 3;
  int wk = (id & 7) * per + (id >> 3);
  int xx = wk % gridDim.x;
  int g2 = wk / gridDim.x;
  int yy = g2 % gridDim.y;
  int zz = g2 / gridDim.y;

  const u16* A;
  const u16* Bm;
  u16* C;
  int ldc;
  if (zz < NH) {
    if (xx >= 6) return;  // MT is 768x768: 6x6 tiles
    A = kT + (size_t)zz * DD;
    Bm = qT + (size_t)zz * DD;
    C = MTp + (size_t)zz * DD;
    ldc = ND;
  } else {
    int b = zz - NH;
    A = vb;
    Bm = xb + (size_t)b * LD;
    C = V2p + (size_t)b * NH * NDH * NL;
    ldc = NL;
  }

  int m0 = yy * 128, n0 = xx * 128;
  int t = threadIdx.x;
  int lane = t & 63, w = t >> 6;
  int m32 = lane & 31, kg = lane >> 5;
  int wm = w >> 1, wn = w & 1;

  const u16* gAb;
  const u16* gBb;
  {
    int r = t / CPR;
    int cc = (t & (CPR - 1)) ^ (r & 7);
    gAb = A + (size_t)(m0 + r) * KDIM + cc * 8;
    gBb = Bm + (size_t)(n0 + r) * KDIM + cc * 8;
  }

  f32x16 acc[2][2];
#pragma unroll
  for (int i = 0; i < 2; i++)
#pragma unroll
    for (int j = 0; j < 2; j++)
#pragma unroll
      for (int r = 0; r < 16; r++) acc[i][j][r] = 0.f;

#pragma unroll 1
  for (int k0 = 0; k0 < KDIM; k0 += BK) {
    __syncthreads();
#pragma unroll
    for (int u = 0; u < 4; u++)
      load16_to_lds(gAb + (size_t)u * 32 * KDIM, &As[(size_t)(u * 256 + w * 64) * 8]);
    gAb += BK;
#pragma unroll
    for (int u = 0; u < 4; u++)
      load16_to_lds(gBb + (size_t)u * 32 * KDIM, &Bs[(size_t)(u * 256 + w * 64) * 8]);
    gBb += BK;
    __syncthreads();

#pragma unroll
    for (int kc = 0; kc < 2; kc++) {
      short8 af[2][2], bfr[2][2];
#pragma unroll
      for (int i = 0; i < 2; i++) {
        int row = wm * 64 + i * 32 + m32;
#pragma unroll
        for (int h = 0; h < 2; h++) {
          int ck = (kc * 4 + h * 2 + kg) ^ (row & 7);
          af[i][h] = *(const short8*)&As[row * BK + ck * 8];
        }
      }
#pragma unroll
      for (int j = 0; j < 2; j++) {
        int row = wn * 64 + j * 32 + m32;
#pragma unroll
        for (int h = 0; h < 2; h++) {
          int ck = (kc * 4 + h * 2 + kg) ^ (row & 7);
          bfr[j][h] = *(const short8*)&Bs[row * BK + ck * 8];
        }
      }
#pragma unroll
      for (int i = 0; i < 2; i++)
#pragma unroll
        for (int j = 0; j < 2; j++) {
          acc[i][j] = __builtin_amdgcn_mfma_f32_32x32x16_bf16(af[i][0], bfr[j][0], acc[i][j], 0, 0, 0);
          acc[i][j] = __builtin_amdgcn_mfma_f32_32x32x16_bf16(af[i][1], bfr[j][1], acc[i][j], 0, 0, 0);
        }
    }
  }

#pragma unroll
  for (int i = 0; i < 2; i++) {
#pragma unroll
    for (int j = 0; j < 2; j++) {
      int colg = n0 + wn * 64 + j * 32 + m32;
#pragma unroll
      for (int r = 0; r < 16; r++) {
        int rowg = m0 + wm * 64 + i * 32 + (r & 3) + 8 * (r >> 2) + 4 * kg;
        C[(size_t)rowg * ldc + colg] = f2bf(acc[i][j][r]);
      }
    }
  }
}

// ---------------- gemm256_8p: 256x256 tile, 8 waves, 8-phase schedule ----------------
// OUTMODE: 0 = f32, 1 = bf16, 2 = bf16(exp(v)) — softmax exp fused into epilogue.
template <int OUTMODE, int KDIM, int LDC>
__global__ __launch_bounds__(512, 2) void gemm256_8p(
    const u16* __restrict__ A, const u16* __restrict__ Bm, void* __restrict__ Cv,
    long sAb, long sAn, long sAz,
    long sBb, long sBn, long sBz,
    long sCb, long sCn, long sCz,
    int p0) {
  constexpr int BK = 64;
  constexpr int NT = KDIM / BK;
  constexpr int NC = NT / 2;
  static_assert(KDIM % 128 == 0 && NC >= 2, "need even #K-tiles and >=2 cycles");
  __shared__ __align__(16) u16 As[2][256 * BK];  // 64 KB
  __shared__ __align__(16) u16 Bs[2][256 * BK];  // 64 KB

  int id = blockIdx.x + gridDim.x * (blockIdx.y + gridDim.y * blockIdx.z);
  int total = gridDim.x * gridDim.y * gridDim.z;
  int xx, yy, zz;
  if ((total & 7) == 0) {
    int per = total >> 3;
    int wk = (id & 7) * per + (id >> 3);
    xx = wk % gridDim.x;
    int g2 = wk / gridDim.x;
    yy = g2 % gridDim.y;
    zz = g2 / gridDim.y;
  } else {
    xx = blockIdx.x; yy = blockIdx.y; zz = blockIdx.z;
  }

  int g = p0 + zz;
  int b = g / NH, n = g % NH;
  A  += (size_t)b * sAb + (size_t)n * sAn + (size_t)zz * sAz;
  Bm += (size_t)b * sBb + (size_t)n * sBn + (size_t)zz * sBz;
  size_t cOff = (size_t)b * sCb + (size_t)n * sCn + (size_t)zz * sCz;

  int m0 = yy * 256, n0 = xx * 256;
  int t = threadIdx.x;
  int lane = t & 63, w = t >> 6;
  int wm = w >> 2, wn = w & 3;
  int l15 = lane & 15, q4 = lane >> 4;

  int r0 = t >> 3;
  int cc0 = (t & 7) ^ (r0 & 7);
  const u16* gA = A + (size_t)(m0 + r0) * KDIM + cc0 * 8;
  const u16* gB = Bm + (size_t)(n0 + r0) * KDIM + cc0 * 8;
  int wslab = w * 512;  // per-wave u16 offset within a 64-row call slab

#define STG_A1(d, h, u, kt) load16_to_lds( \
    gA + (size_t)((h) * 128 + (u) * 64) * KDIM + (size_t)(kt) * BK, \
    &As[d][((h) * 128 + (u) * 64) * BK + wslab])
#define STG_B1(d, h, u, kt) load16_to_lds( \
    gB + (size_t)((h) * 128 + (u) * 64) * KDIM + (size_t)(kt) * BK, \
    &Bs[d][((h) * 128 + (u) * 64) * BK + wslab])
#define STG_A2(d, h, kt) do { STG_A1(d, h, 0, kt); STG_A1(d, h, 1, kt); } while (0)
#define STG_B2(d, h, kt) do { STG_B1(d, h, 0, kt); STG_B1(d, h, 1, kt); } while (0)

#define READ_A(d, qm, dst) do { \
  _Pragma("unroll") for (int fm = 0; fm < 4; fm++) { \
    int row = (qm) * 128 + wm * 64 + fm * 16 + l15; \
    _Pragma("unroll") for (int ks = 0; ks < 2; ks++) { \
      int ck = (ks * 4 + q4) ^ (row & 7); \
      dst[fm][ks] = *(const short8*)&As[d][row * BK + ck * 8]; \
    } \
  } \
} while (0)

#define READ_B(d, qn, dst) do { \
  _Pragma("unroll") for (int fn = 0; fn < 2; fn++) { \
    int row = (qn) * 128 + wn * 32 + fn * 16 + l15; \
    _Pragma("unroll") for (int ks = 0; ks < 2; ks++) { \
      int ck = (ks * 4 + q4) ^ (row & 7); \
      dst[fn][ks] = *(const short8*)&Bs[d][row * BK + ck * 8]; \
    } \
  } \
} while (0)

#define MF_Q(qm, qn, AR, BR) do { \
  __builtin_amdgcn_s_setprio(1); \
  _Pragma("unroll") for (int ks = 0; ks < 2; ks++) \
    _Pragma("unroll") for (int fm = 0; fm < 4; fm++) \
      _Pragma("unroll") for (int fn = 0; fn < 2; fn++) \
        acc[qm][qn][fm][fn] = __builtin_amdgcn_mfma_f32_16x16x32_bf16( \
            AR[fm][ks], BR[fn][ks], acc[qm][qn][fm][fn], 0, 0, 0); \
  __builtin_amdgcn_s_setprio(0); \
} while (0)

#define PH_SYNC() do { \
  __builtin_amdgcn_s_barrier(); \
  asm volatile("s_waitcnt lgkmcnt(0)" ::: "memory"); \
  __builtin_amdgcn_sched_barrier(0); \
} while (0)
#define PH_END() do { \
  __builtin_amdgcn_s_barrier(); \
  __builtin_amdgcn_sched_barrier(0); \
} while (0)

  f32x4 acc[2][2][4][2];
#pragma unroll
  for (int qm = 0; qm < 2; qm++)
#pragma unroll
    for (int qn = 0; qn < 2; qn++)
#pragma unroll
      for (int fm = 0; fm < 4; fm++)
#pragma unroll
        for (int fn = 0; fn < 2; fn++)
          acc[qm][qn][fm][fn] = (f32x4){0.f, 0.f, 0.f, 0.f};

  // prologue: tile0 fully -> buf0 (8 calls); tile1 h0 halves -> buf1 (4 calls)
  STG_A2(0, 0, 0); STG_A2(0, 1, 0);
  STG_B2(0, 0, 0); STG_B2(0, 1, 0);
  STG_A2(1, 0, 1); STG_B2(1, 0, 1);
  asm volatile("s_waitcnt vmcnt(4)" ::: "memory");
  __builtin_amdgcn_s_barrier();
  __builtin_amdgcn_sched_barrier(0);

#pragma unroll 1
  for (int cyc = 0; cyc < NC; ++cyc) {
    int t0 = cyc * 2;
    bool full = (cyc + 1 < NC);
    short8 af0[4][2], af1[4][2], bq0[2][2], bq1[2][2];

    // ---- K-tile t0 from buf0 ----
    READ_A(0, 0, af0); READ_B(0, 0, bq0);
    STG_A2(1, 1, t0 + 1);
    PH_SYNC(); MF_Q(0, 0, af0, bq0); PH_END();
    READ_B(0, 1, bq1);
    STG_B2(1, 1, t0 + 1);
    PH_SYNC(); MF_Q(0, 1, af0, bq1); PH_END();
    READ_A(0, 1, af1);
    if (full) STG_A2(0, 0, t0 + 2);
    PH_SYNC(); MF_Q(1, 0, af1, bq0); PH_END();
    if (full) STG_B2(0, 0, t0 + 2);
    __builtin_amdgcn_s_barrier();
    MF_Q(1, 1, af1, bq1);
    __builtin_amdgcn_sched_barrier(0);
    if (full) asm volatile("s_waitcnt vmcnt(4)" ::: "memory");
    else      asm volatile("s_waitcnt vmcnt(0)" ::: "memory");
    PH_END();

    // ---- K-tile t0+1 from buf1 ----
    READ_A(1, 0, af0); READ_B(1, 0, bq0);
    if (full) STG_A2(0, 1, t0 + 2);
    PH_SYNC(); MF_Q(0, 0, af0, bq0); PH_END();
    READ_B(1, 1, bq1);
    if (full) STG_B2(0, 1, t0 + 2);
    PH_SYNC(); MF_Q(0, 1, af0, bq1); PH_END();
    READ_A(1, 1, af1);
    if (full) STG_A2(1, 0, t0 + 3);
    PH_SYNC(); MF_Q(1, 0, af1, bq0); PH_END();
    if (full) {
      STG_B2(1, 0, t0 + 3);
      __builtin_amdgcn_s_barrier();
      MF_Q(1, 1, af1, bq1);
      __builtin_amdgcn_sched_barrier(0);
      asm volatile("s_waitcnt vmcnt(4)" ::: "memory");
      PH_END();
    } else {
      __builtin_amdgcn_s_barrier();
      MF_Q(1, 1, af1, bq1);
    }
  }

  // epilogue: 16x16 frag C/D map: row = q4*4 + r, col = l15
#pragma unroll
  for (int qm = 0; qm < 2; qm++)
#pragma unroll
    for (int qn = 0; qn < 2; qn++)
#pragma unroll
      for (int fm = 0; fm < 4; fm++)
#pragma unroll
        for (int fn = 0; fn < 2; fn++) {
          int colg = n0 + qn * 128 + wn * 32 + fn * 16 + l15;
#pragma unroll
          for (int r = 0; r < 4; r++) {
            int rowg = m0 + qm * 128 + wm * 64 + fm * 16 + q4 * 4 + r;
            float vv = acc[qm][qn][fm][fn][r];
            if (OUTMODE == 2) vv = __expf(vv);
            if (OUTMODE >= 1) {
              ((u16*)Cv)[cOff + (size_t)rowg * LDC + colg] = f2bf(vv);
            } else {
              ((float*)Cv)[cOff + (size_t)rowg * LDC + colg] = vv;
            }
          }
        }
#undef STG_A1
#undef STG_B1
#undef STG_A2
#undef STG_B2
#undef READ_A
#undef READ_B
#undef MF_Q
#undef PH_SYNC
#undef PH_END
}

// ---------------- fused PV (+ divide) over precomputed P = exp(S) ----------------
__global__ __launch_bounds__(256) void softmax_pv_kernel(
    const u16* __restrict__ Pb, const u16* __restrict__ V2, float* __restrict__ out,
    int p0) {
  __shared__ __align__(16) u16 Ps[64 * 128];  // 16 KB
  __shared__ __align__(16) u16 Vs[64 * 128];  // 16 KB

  int id = blockIdx.x + gridDim.x * blockIdx.y;
  int total = gridDim.x * gridDim.y;
  int xx, zz;
  if ((total & 7) == 0) {
    int per = total >> 3;
    int wk = (id & 7) * per + (id >> 3);
    xx = wk & 15; zz = wk >> 4;
  } else {
    xx = blockIdx.x; zz = blockIdx.y;
  }

  int g = p0 + zz;
  int b = g / NH, n = g % NH;
  const u16* S = Pb + (size_t)zz * NL * NL;
  const u16* V = V2 + (size_t)g * NDH * NL;

  int l0 = xx * 64;
  int t = threadIdx.x;
  int lane = t & 63, w = t >> 6;
  int row16 = lane & 15, q = lane >> 4;
  int rs = row16 & 7;

  f32x4 acc[5];
#pragma unroll
  for (int j = 0; j < 5; j++) acc[j] = (f32x4){0.f, 0.f, 0.f, 0.f};

  short8 onesf;
  {
    short val = (row16 == 0) ? (short)0x3F80 : (short)0;
#pragma unroll
    for (int e = 0; e < 8; e++) onesf[e] = val;
  }

  const u16* ssrc[4];
  const u16* vsrc[4];
#pragma unroll
  for (int u = 0; u < 4; u++) {
    int c = u * 256 + t;
    int r = c >> 4, cc = (c & 15) ^ (r & 7);
    ssrc[u] = S + (size_t)(l0 + r) * NL + cc * 8;
    vsrc[u] = V + (size_t)r * NL + cc * 8;
  }

#pragma unroll 1
  for (int mt = 0; mt < 8; mt++) {
    int mo = mt * 128;
    __syncthreads();
#pragma unroll
    for (int u = 0; u < 4; u++)
      load16_to_lds(ssrc[u] + mo, &Ps[(size_t)(u * 256 + w * 64) * 8]);
#pragma unroll
    for (int u = 0; u < 4; u++)
      load16_to_lds(vsrc[u] + mo, &Vs[(size_t)(u * 256 + w * 64) * 8]);
    __syncthreads();

#pragma unroll
    for (int kk = 0; kk < 4; kk++) {
      int ch = ((kk * 4 + q) ^ rs) * 16;
      int lrow = w * 16 + row16;
      // P already exp'd (fused into the Sb GEMM epilogue) — feed raw.
      short8 paf = *(const short8*)((const char*)Ps + lrow * 256 + ch);
      short8 bfr[4];
#pragma unroll
      for (int j = 0; j < 4; j++) {
        int dh = j * 16 + row16;
        bfr[j] = *(const short8*)((const char*)Vs + dh * 256 + ch);
      }
#pragma unroll
      for (int j = 0; j < 4; j++)
        acc[j] = __builtin_amdgcn_mfma_f32_16x16x32_bf16(paf, bfr[j], acc[j], 0, 0, 0);
      acc[4] = __builtin_amdgcn_mfma_f32_16x16x32_bf16(paf, onesf, acc[4], 0, 0, 0);
    }
  }

#pragma unroll
  for (int r = 0; r < 4; r++) {
    float sum = __shfl(acc[4][r], lane & 48, 64);
    float inv = 1.0f / sum;
    int row = l0 + w * 16 + q * 4 + r;
    float* op = out + ((size_t)b * NL + row) * ND + n * NDH;
#pragma unroll
    for (int j = 0; j < 4; j++)
      op[j * 16 + row16] = acc[j][r] * inv;
  }
}

extern "C" void kernel_launch(void* const* d_in, const int* in_sizes, int n_in,
                              void* d_out, int out_size, void* d_ws, size_t ws_size,
                              hipStream_t stream) {
  (void)in_sizes; (void)n_in; (void)out_size;
  const float* x  = (const float*)d_in[0];
  const float* kI = (const float*)d_in[1];
  const float* qI = (const float*)d_in[2];
  const float* vI = (const float*)d_in[3];
  float* out = (float*)d_out;

  size_t off = 0;
  char* wsb = (char*)d_ws;
  auto alloc = [&](size_t bytes) -> char* {
    char* p = wsb + off;
    off += (bytes + 255) & ~(size_t)255;
    return p;
  };
  // ---- fixed (live across whole launch) ----
  u16* xb = (u16*)alloc((size_t)NB * NL * ND * 2);        // 12.6 MB
  u16* vb = (u16*)alloc((size_t)NH * NDH * ND * 2);       //  2.4 MB
  u16* MT = (u16*)alloc((size_t)NH * ND * ND * 2);        // 28.3 MB
  u16* V2 = (u16*)alloc((size_t)NB * NH * NDH * NL * 2);  //  6.3 MB
  size_t fixedSz = off;

  // ---- scratch: qT/kT live only until gemm_prep; T/Sb overlay the same region.
  u16* qT = (u16*)alloc((size_t)NH * ND * ND * 2);        // 28.3 MB
  u16* kT = (u16*)alloc((size_t)NH * ND * ND * 2);        // 28.3 MB
  size_t scratchEndQK = off;

  const size_t Tsz  = (size_t)NL * ND * 2;
  const size_t Ssz  = (size_t)NL * NL * 2;
  const size_t perPair = Tsz + Ssz;

  int chunk = NB * NH;  // 48
  {
    size_t avail = ws_size > fixedSz ? ws_size - fixedSz : 0;
    size_t maxChunk = avail / perPair;
    if (maxChunk < 1) maxChunk = 1;
    if (maxChunk < (size_t)chunk) {
      int passes = (int)(((size_t)NB * NH + maxChunk - 1) / maxChunk);
      chunk = (NB * NH + passes - 1) / passes;
    }
  }
  off = fixedSz;
  u16* T  = (u16*)alloc((size_t)chunk * Tsz);
  u16* Sb = (u16*)alloc((size_t)chunk * Ssz);
  if (off < scratchEndQK) off = scratchEndQK;

  const long DD  = (long)ND * ND;
  const long LD  = (long)NL * ND;
  const long LL  = (long)NL * NL;

  {
    int n4A = NB * NL * ND / 4;
    int n4B = NH * NDH * ND / 4;
    // transposes (z<24) + casts (z==24) in one dispatch
    prep_inputs_kernel<<<dim3(24, 24, 2 * NH + 1), dim3(256), 0, stream>>>(
        qI, kI, qT, kT, x, xb, n4A, vI, vb, n4B);
  }

  // MT (zz<12) + batched V2 (zz>=12) in one dispatch: grid 8x6x16 = 768 blocks
  gemm_prep<<<dim3(8, 6, 16), dim3(256), 0, stream>>>(kT, qT, MT, vb, xb, V2);

  for (int p0 = 0; p0 < NB * NH; p0 += chunk) {
    int c = NB * NH - p0;
    if (c > chunk) c = chunk;
    // T[z][l][e] = sum_d xb[b][l][d] * MT[n][e][d]  (1024x768, K=768) — 128^2, 4 blk/CU
    gemm_bt<true, 2, 2, 768, ND><<<dim3(6, 8, c), dim3(256), 0, stream>>>(
        xb, MT, T,
        LD, 0, 0,  0, DD, 0,  0, 0, LD, p0);
    // P[z][l][m] = exp(sum_e T[z][l][e]*xb[b][m][e])  (1024x1024, K=768) — 8-phase 256^2
    gemm256_8p<2, 768, NL><<<dim3(4, 4, c), dim3(512), 0, stream>>>(
        T, xb, Sb,
        0, 0, LD,  LD, 0, 0,  0, 0, LL, p0);
    // PV + divide -> writes out directly
    softmax_pv_kernel<<<dim3(16, c), dim3(256), 0, stream>>>(Sb, V2, out, p0);
  }
}